// Round 2
// baseline (360.851 us; speedup 1.0000x reference)
//
#include <hip/hip_runtime.h>
#include <stdint.h>

// Problem constants
#define NB 4
#define NL 2048
#define NE 1024
#define NH 16
#define ND 64
#define NM (NB*NL)   // 8192 rows

typedef float f32x4 __attribute__((ext_vector_type(4)));
typedef short s16x8 __attribute__((ext_vector_type(8)));

__device__ __forceinline__ unsigned short f2b(float f) {
  uint32_t u = __float_as_uint(f);
  u += 0x7fffu + ((u >> 16) & 1u);   // RNE; inputs are finite
  return (unsigned short)(u >> 16);
}

__device__ __forceinline__ void gload16(const void* g, void* l) {
  __builtin_amdgcn_global_load_lds((const __attribute__((address_space(1))) void*)g,
                                   (__attribute__((address_space(3))) void*)l, 16, 0, 0);
}

// ---------------- fp32 -> bf16 conversion (vectorized, grid-stride) --------
__global__ void cvt_kernel(const float* __restrict__ in, unsigned short* __restrict__ out, int n8) {
  int stride = gridDim.x * blockDim.x;
  for (int i = blockIdx.x * blockDim.x + threadIdx.x; i < n8; i += stride) {
    const float4* p = (const float4*)in + (size_t)i * 2;
    float4 a = p[0], b = p[1];
    s16x8 r;
    r[0] = (short)f2b(a.x); r[1] = (short)f2b(a.y); r[2] = (short)f2b(a.z); r[3] = (short)f2b(a.w);
    r[4] = (short)f2b(b.x); r[5] = (short)f2b(b.y); r[6] = (short)f2b(b.z); r[7] = (short)f2b(b.w);
    *((s16x8*)out + i) = r;
  }
}

// 4 weight matrices in one launch; blockIdx.y selects the matrix.
__global__ void cvt4_kernel(const float* __restrict__ w0, const float* __restrict__ w1,
                            const float* __restrict__ w2, const float* __restrict__ w3,
                            unsigned short* __restrict__ o0, unsigned short* __restrict__ o1,
                            unsigned short* __restrict__ o2, unsigned short* __restrict__ o3,
                            int n8) {
  const int y = blockIdx.y;
  const float* in = (y == 0) ? w0 : (y == 1) ? w1 : (y == 2) ? w2 : w3;
  unsigned short* out = (y == 0) ? o0 : (y == 1) ? o1 : (y == 2) ? o2 : o3;
  int stride = gridDim.x * blockDim.x;
  for (int i = blockIdx.x * blockDim.x + threadIdx.x; i < n8; i += stride) {
    const float4* p = (const float4*)in + (size_t)i * 2;
    float4 a = p[0], b = p[1];
    s16x8 r;
    r[0] = (short)f2b(a.x); r[1] = (short)f2b(a.y); r[2] = (short)f2b(a.z); r[3] = (short)f2b(a.w);
    r[4] = (short)f2b(b.x); r[5] = (short)f2b(b.y); r[6] = (short)f2b(b.z); r[7] = (short)f2b(b.w);
    *((s16x8*)out + i) = r;
  }
}

// ---------------- B^T-input bf16 GEMM, 128x128 tile, BK=64 -----------------
// C[m][n] = sum_k A[m][k]*W[n][k] + bias[n]
// MODE 0: fused QKV projection. blockIdx.x: 0-7 -> Q, 8-15 -> K, 16-23 -> V.
//         Q,K written [B,H,L,64] bf16; V written transposed [B,H,64,L] bf16.
// MODE 1: output projection, fp32 out [M][NE] + bias.
template<int MODE>
__launch_bounds__(256, 2)
__global__ void gemm_bt(const unsigned short* __restrict__ A,
                        const unsigned short* __restrict__ W0,
                        const unsigned short* __restrict__ W1,
                        const unsigned short* __restrict__ W2,
                        const float* __restrict__ b0,
                        const float* __restrict__ b1,
                        const float* __restrict__ b2,
                        unsigned short* __restrict__ O0,
                        unsigned short* __restrict__ O1,
                        unsigned short* __restrict__ O2,
                        float* __restrict__ fout)
{
  __shared__ alignas(16) char smem[32768];
  char* sA = smem;            // [128][64] bf16, XOR-swizzled
  char* sB = smem + 16384;    // [128][64] bf16, XOR-swizzled

  const int tid = threadIdx.x;
  const int lane = tid & 63;
  const int wid = tid >> 6;
  const int bx = blockIdx.x, by = blockIdx.y;
  const int m0 = by * 128;

  int which = 0;
  const unsigned short* Wsel;
  const float* bias;
  int n0;
  if (MODE == 0) {
    which = bx >> 3;
    Wsel = (which == 0) ? W0 : ((which == 1) ? W1 : W2);
    bias = (which == 0) ? b0 : ((which == 1) ? b1 : b2);
    n0 = (bx & 7) * 128;
  } else {
    Wsel = W0; bias = b0; n0 = bx * 128;
  }

  const int wr = (wid >> 1) * 64;
  const int wc = (wid & 1) * 64;
  int aaddr[4], baddr[4];
#pragma unroll
  for (int m = 0; m < 4; ++m) {
    int ra = wr + m * 16 + (lane & 15);
    aaddr[m] = ra * 128 + (((lane >> 4) * 16) ^ ((ra & 7) << 4));
    int rb = wc + m * 16 + (lane & 15);
    baddr[m] = rb * 128 + (((lane >> 4) * 16) ^ ((rb & 7) << 4));
  }

  f32x4 acc[4][4] = {};
  const int c0 = wid * 64 + lane;

  for (int kt = 0; kt < 16; ++kt) {
    const int k0 = kt * 64;
#pragma unroll
    for (int it = 0; it < 4; ++it) {
      int c = it * 256 + c0;              // 16B chunk id, dest byte = c*16
      int row = c >> 3;                   // 128B per row
      int sb = ((((c & 7) << 4)) ^ ((row & 7) << 4)) >> 1;  // inverse-swizzled src elem
      gload16(A    + (size_t)(m0 + row) * NE + k0 + sb, sA + it * 4096 + wid * 1024);
      gload16(Wsel + (size_t)(n0 + row) * NE + k0 + sb, sB + it * 4096 + wid * 1024);
    }
    __syncthreads();
#pragma unroll
    for (int kk = 0; kk < 2; ++kk) {
      s16x8 af[4], bf[4];
#pragma unroll
      for (int m = 0; m < 4; ++m) af[m] = *(const s16x8*)(sA + (aaddr[m] ^ (kk << 6)));
#pragma unroll
      for (int n = 0; n < 4; ++n) bf[n] = *(const s16x8*)(sB + (baddr[n] ^ (kk << 6)));
#pragma unroll
      for (int m = 0; m < 4; ++m)
#pragma unroll
        for (int n = 0; n < 4; ++n)
          acc[m][n] = __builtin_amdgcn_mfma_f32_16x16x32_bf16(af[m], bf[n], acc[m][n], 0, 0, 0);
    }
    __syncthreads();
  }

  // Epilogue. C/D layout: col = lane&15, row = (lane>>4)*4 + reg (m89/m91).
#pragma unroll
  for (int m = 0; m < 4; ++m) {
    const int row0 = m0 + wr + m * 16 + ((lane >> 4) << 2);
#pragma unroll
    for (int n = 0; n < 4; ++n) {
      const int col = n0 + wc + n * 16 + (lane & 15);
      const float bv = bias[col];
      if (MODE == 1) {
#pragma unroll
        for (int r = 0; r < 4; ++r)
          fout[(size_t)(row0 + r) * NE + col] = acc[m][n][r] + bv;
      } else {
        const int b = row0 >> 11;
        const int l = row0 & 2047;
        const int h = col >> 6;
        const int d = col & 63;
        if (which < 2) {
          unsigned short* dst = (which == 0) ? O0 : O1;
#pragma unroll
          for (int r = 0; r < 4; ++r)
            dst[((size_t)(b * NH + h) * NL + (l + r)) * ND + d] = f2b(acc[m][n][r] + bv);
        } else {
          // V transposed: [B,H,64,L]; 4 regs are 4 consecutive l -> pack 8B store
          ushort4 pk;
          pk.x = f2b(acc[m][n][0] + bv);
          pk.y = f2b(acc[m][n][1] + bv);
          pk.z = f2b(acc[m][n][2] + bv);
          pk.w = f2b(acc[m][n][3] + bv);
          *(ushort4*)(O2 + ((size_t)(b * NH + h) * ND + d) * NL + l) = pk;
        }
      }
    }
  }
}

// ---------------- flash attention fwd, per (b,h), q-tile 128 ----------------
// Q,K: [B,H,L,64] bf16; Vt: [B,H,64,L] bf16; AO out: [B,L,E] bf16.
__launch_bounds__(256, 2)
__global__ void attn_kernel(const unsigned short* __restrict__ Q,
                            const unsigned short* __restrict__ K,
                            const unsigned short* __restrict__ Vt,
                            unsigned short* __restrict__ AO)
{
  __shared__ alignas(16) char smem[65536];
  char* sK = smem;            // [128][64]  bf16 swizzled, 16KB
  char* sV = smem + 16384;    // [64][128]  bf16 swizzled, 16KB
  char* sP = smem + 32768;    // 4 x [32][128] bf16 swizzled, 32KB

  const int tid = threadIdx.x;
  const int lane = tid & 63;
  const int wid = tid >> 6;
  const int qt = blockIdx.x;
  const int bh = blockIdx.y;
  const int b = bh >> 4;
  const int h = bh & 15;
  const size_t base = (size_t)bh * NL * ND;
  const int q0 = qt * 128 + wid * 32;     // this wave's 32 q rows

  // Q fragments held in registers for the whole kernel
  s16x8 qf[2][2];
#pragma unroll
  for (int m = 0; m < 2; ++m)
#pragma unroll
    for (int kk = 0; kk < 2; ++kk)
      qf[m][kk] = *(const s16x8*)(Q + base + (size_t)(q0 + m * 16 + (lane & 15)) * ND
                                  + kk * 32 + (lane >> 4) * 8);

  f32x4 o[2][4] = {};
  float rm[2][4], rl[2][4];
#pragma unroll
  for (int m = 0; m < 2; ++m)
#pragma unroll
    for (int r = 0; r < 4; ++r) { rm[m][r] = -1e30f; rl[m][r] = 0.f; }

  int kaddr[8], vaddr[4], paddr[2];
#pragma unroll
  for (int n = 0; n < 8; ++n) {
    int rk = n * 16 + (lane & 15);
    kaddr[n] = rk * 128 + (((lane >> 4) * 16) ^ ((rk & 7) << 4));
  }
#pragma unroll
  for (int n = 0; n < 4; ++n) {
    int rd = n * 16 + (lane & 15);
    vaddr[n] = rd * 256 + (((lane >> 4) * 16) ^ ((rd & 7) << 4));
  }
#pragma unroll
  for (int m = 0; m < 2; ++m) {
    int rp = m * 16 + (lane & 15);
    paddr[m] = wid * 8192 + rp * 256 + (((lane >> 4) * 16) ^ ((rp & 7) << 4));
  }
  const int c0 = wid * 64 + lane;
  const float SC = 0.125f * 1.44269504088896f;   // scale * log2(e)

  for (int t = 0; t < 16; ++t) {
    const int kv0 = t * 128;
#pragma unroll
    for (int it = 0; it < 4; ++it) {
      int c = it * 256 + c0;
      {
        int row = c >> 3;
        int sb = ((((c & 7) << 4)) ^ ((row & 7) << 4)) >> 1;
        gload16(K + base + (size_t)(kv0 + row) * ND + sb, sK + it * 4096 + wid * 1024);
      }
      {
        int d = c >> 4;
        int sb = ((((c & 15) << 4)) ^ ((d & 7) << 4)) >> 1;
        gload16(Vt + base + (size_t)d * NL + kv0 + sb, sV + it * 4096 + wid * 1024);
      }
    }
    __syncthreads();

    // S = Q K^T for this wave's 32 rows x 128 kv cols
    f32x4 s[2][8] = {};
#pragma unroll
    for (int kk = 0; kk < 2; ++kk) {
      s16x8 kf[8];
#pragma unroll
      for (int n = 0; n < 8; ++n) kf[n] = *(const s16x8*)(sK + (kaddr[n] ^ (kk << 6)));
#pragma unroll
      for (int m = 0; m < 2; ++m)
#pragma unroll
        for (int n = 0; n < 8; ++n)
          s[m][n] = __builtin_amdgcn_mfma_f32_16x16x32_bf16(qf[m][kk], kf[n], s[m][n], 0, 0, 0);
    }

    // online softmax, wave-parallel (16-lane shfl reduce per row group)
#pragma unroll
    for (int m = 0; m < 2; ++m)
#pragma unroll
      for (int r = 0; r < 4; ++r) {
        float mx = s[m][0][r];
#pragma unroll
        for (int n = 1; n < 8; ++n) mx = fmaxf(mx, s[m][n][r]);
        mx *= SC;
#pragma unroll
        for (int off = 1; off < 16; off <<= 1) mx = fmaxf(mx, __shfl_xor(mx, off));
        float mnew = fmaxf(rm[m][r], mx);
        float alpha = __builtin_amdgcn_exp2f(rm[m][r] - mnew);
        rm[m][r] = mnew;
        float ts = 0.f;
        const int rr = m * 16 + ((lane >> 4) << 2) + r;
        const int pw = wid * 8192 + rr * 256;
        const int swz = (rr & 7) << 4;
#pragma unroll
        for (int n = 0; n < 8; ++n) {
          float p = __builtin_amdgcn_exp2f(s[m][n][r] * SC - mnew);
          ts += p;
          *(unsigned short*)(sP + pw + ((n * 32 + ((lane & 15) << 1)) ^ swz)) = f2b(p);
        }
#pragma unroll
        for (int off = 1; off < 16; off <<= 1) ts += __shfl_xor(ts, off);
        rl[m][r] = rl[m][r] * alpha + ts;
#pragma unroll
        for (int n = 0; n < 4; ++n) o[m][n][r] *= alpha;
      }

    // O += P V   (P from per-wave LDS slice, V from swizzled Vt tile)
#pragma unroll
    for (int ks = 0; ks < 4; ++ks) {
      s16x8 pf[2], vf[4];
#pragma unroll
      for (int m = 0; m < 2; ++m) pf[m] = *(const s16x8*)(sP + (paddr[m] ^ (ks << 6)));
#pragma unroll
      for (int n = 0; n < 4; ++n) vf[n] = *(const s16x8*)(sV + (vaddr[n] ^ (ks << 6)));
#pragma unroll
      for (int m = 0; m < 2; ++m)
#pragma unroll
        for (int n = 0; n < 4; ++n)
          o[m][n] = __builtin_amdgcn_mfma_f32_16x16x32_bf16(pf[m], vf[n], o[m][n], 0, 0, 0);
    }
    __syncthreads();
  }

  // normalize + write [B,L,E] bf16
#pragma unroll
  for (int m = 0; m < 2; ++m)
#pragma unroll
    for (int r = 0; r < 4; ++r) {
      const float inv = 1.0f / rl[m][r];
      const int qrow = q0 + m * 16 + ((lane >> 4) << 2) + r;
#pragma unroll
      for (int n = 0; n < 4; ++n) {
        const int col = h * 64 + n * 16 + (lane & 15);
        AO[(size_t)(b * NL + qrow) * NE + col] = f2b(o[m][n][r] * inv);
      }
    }
}

// ---------------------------------------------------------------------------
extern "C" void kernel_launch(void* const* d_in, const int* in_sizes, int n_in,
                              void* d_out, int out_size, void* d_ws, size_t ws_size,
                              hipStream_t stream) {
  const float* x  = (const float*)d_in[0];
  const float* Wq = (const float*)d_in[1];
  const float* bq = (const float*)d_in[2];
  const float* Wk = (const float*)d_in[3];
  const float* bk = (const float*)d_in[4];
  const float* Wv = (const float*)d_in[5];
  const float* bv = (const float*)d_in[6];
  const float* Wo = (const float*)d_in[7];
  const float* bo = (const float*)d_in[8];
  float* out = (float*)d_out;
  char* ws = (char*)d_ws;

  // Workspace layout (72 MB):
  //   [ 0,16) MB : xb  (x bf16)      -- dead after gemm<0>; reused as AOw
  //   [16,18) MB : wqb   [18,20): wkb   [20,22): wvb   [22,24): wob
  //   [24,40) MB : Qw [B,H,L,64]
  //   [40,56) MB : Kw [B,H,L,64]
  //   [56,72) MB : Vtw [B,H,64,L]
  unsigned short* xb  = (unsigned short*)(ws);
  unsigned short* AOw = (unsigned short*)(ws);                      // aliases xb
  unsigned short* wqb = (unsigned short*)(ws + (16u << 20));
  unsigned short* wkb = (unsigned short*)(ws + (18u << 20));
  unsigned short* wvb = (unsigned short*)(ws + (20u << 20));
  unsigned short* wob = (unsigned short*)(ws + (22u << 20));
  unsigned short* Qw  = (unsigned short*)(ws + (24u << 20));
  unsigned short* Kw  = (unsigned short*)(ws + (40u << 20));
  unsigned short* Vtw = (unsigned short*)(ws + (56u << 20));
  (void)in_sizes; (void)n_in; (void)out_size; (void)ws_size;

  cvt_kernel<<<1024, 256, 0, stream>>>(x, xb, (NM * NE) / 8);
  cvt4_kernel<<<dim3(128, 4), 256, 0, stream>>>(Wq, Wk, Wv, Wo,
                                                wqb, wkb, wvb, wob, (NE * NE) / 8);

  gemm_bt<0><<<dim3(24, 64), 256, 0, stream>>>(xb, wqb, wkb, wvb, bq, bk, bv,
                                               Qw, Kw, Vtw, nullptr);
  attn_kernel<<<dim3(16, 64), 256, 0, stream>>>(Qw, Kw, Vtw, AOw);
  gemm_bt<1><<<dim3(8, 64), 256, 0, stream>>>(AOw, wob, nullptr, nullptr, bo,
                                              nullptr, nullptr,
                                              nullptr, nullptr, nullptr, out);
}

// Round 3
// 313.647 us; speedup vs baseline: 1.1505x; 1.1505x over previous
//
#include <hip/hip_runtime.h>
#include <stdint.h>

// Problem constants
#define NB 4
#define NL 2048
#define NE 1024
#define NH 16
#define ND 64
#define NM (NB*NL)   // 8192 rows

typedef float f32x4 __attribute__((ext_vector_type(4)));
typedef short s16x8 __attribute__((ext_vector_type(8)));

__device__ __forceinline__ unsigned short f2b(float f) {
  uint32_t u = __float_as_uint(f);
  u += 0x7fffu + ((u >> 16) & 1u);   // RNE; inputs are finite
  return (unsigned short)(u >> 16);
}

__device__ __forceinline__ uint32_t pk2(float a, float b) {
  return (uint32_t)f2b(a) | ((uint32_t)f2b(b) << 16);
}

__device__ __forceinline__ void gload16(const void* g, void* l) {
  __builtin_amdgcn_global_load_lds((const __attribute__((address_space(1))) void*)g,
                                   (__attribute__((address_space(3))) void*)l, 16, 0, 0);
}

// ---------------- fp32 -> bf16 conversion (vectorized, grid-stride) --------
__global__ void cvt_kernel(const float* __restrict__ in, unsigned short* __restrict__ out, int n8) {
  int stride = gridDim.x * blockDim.x;
  for (int i = blockIdx.x * blockDim.x + threadIdx.x; i < n8; i += stride) {
    const float4* p = (const float4*)in + (size_t)i * 2;
    float4 a = p[0], b = p[1];
    s16x8 r;
    r[0] = (short)f2b(a.x); r[1] = (short)f2b(a.y); r[2] = (short)f2b(a.z); r[3] = (short)f2b(a.w);
    r[4] = (short)f2b(b.x); r[5] = (short)f2b(b.y); r[6] = (short)f2b(b.z); r[7] = (short)f2b(b.w);
    *((s16x8*)out + i) = r;
  }
}

// 4 weight matrices in one launch; blockIdx.y selects the matrix.
__global__ void cvt4_kernel(const float* __restrict__ w0, const float* __restrict__ w1,
                            const float* __restrict__ w2, const float* __restrict__ w3,
                            unsigned short* __restrict__ o0, unsigned short* __restrict__ o1,
                            unsigned short* __restrict__ o2, unsigned short* __restrict__ o3,
                            int n8) {
  const int y = blockIdx.y;
  const float* in = (y == 0) ? w0 : (y == 1) ? w1 : (y == 2) ? w2 : w3;
  unsigned short* out = (y == 0) ? o0 : (y == 1) ? o1 : (y == 2) ? o2 : o3;
  int stride = gridDim.x * blockDim.x;
  for (int i = blockIdx.x * blockDim.x + threadIdx.x; i < n8; i += stride) {
    const float4* p = (const float4*)in + (size_t)i * 2;
    float4 a = p[0], b = p[1];
    s16x8 r;
    r[0] = (short)f2b(a.x); r[1] = (short)f2b(a.y); r[2] = (short)f2b(a.z); r[3] = (short)f2b(a.w);
    r[4] = (short)f2b(b.x); r[5] = (short)f2b(b.y); r[6] = (short)f2b(b.z); r[7] = (short)f2b(b.w);
    *((s16x8*)out + i) = r;
  }
}

// ---------------- B^T-input bf16 GEMM, 128x128 tile, BK=64 -----------------
// C[m][n] = sum_k A[m][k]*W[n][k] + bias[n]
// MODE 0: fused QKV projection. blockIdx.x: 0-7 -> Q, 8-15 -> K, 16-23 -> V.
//         Q,K written [B,H,L,64] bf16 (Q pre-scaled by 0.125*log2e);
//         V written transposed [B,H,64,L] bf16.
// MODE 1: output projection, fp32 out [M][NE] + bias.
template<int MODE>
__launch_bounds__(256, 3)
__global__ void gemm_bt(const unsigned short* __restrict__ A,
                        const unsigned short* __restrict__ W0,
                        const unsigned short* __restrict__ W1,
                        const unsigned short* __restrict__ W2,
                        const float* __restrict__ b0,
                        const float* __restrict__ b1,
                        const float* __restrict__ b2,
                        unsigned short* __restrict__ O0,
                        unsigned short* __restrict__ O1,
                        unsigned short* __restrict__ O2,
                        float* __restrict__ fout)
{
  __shared__ alignas(16) char smem[32768];
  char* sA = smem;            // [128][64] bf16, XOR-swizzled
  char* sB = smem + 16384;    // [128][64] bf16, XOR-swizzled

  const int tid = threadIdx.x;
  const int lane = tid & 63;
  const int wid = tid >> 6;
  const int bx = blockIdx.x, by = blockIdx.y;
  const int m0 = by * 128;

  int which = 0;
  const unsigned short* Wsel;
  const float* bias;
  int n0;
  if (MODE == 0) {
    which = bx >> 3;
    Wsel = (which == 0) ? W0 : ((which == 1) ? W1 : W2);
    bias = (which == 0) ? b0 : ((which == 1) ? b1 : b2);
    n0 = (bx & 7) * 128;
  } else {
    Wsel = W0; bias = b0; n0 = bx * 128;
  }

  const int wr = (wid >> 1) * 64;
  const int wc = (wid & 1) * 64;
  int aaddr[4], baddr[4];
#pragma unroll
  for (int m = 0; m < 4; ++m) {
    int ra = wr + m * 16 + (lane & 15);
    aaddr[m] = ra * 128 + (((lane >> 4) * 16) ^ ((ra & 7) << 4));
    int rb = wc + m * 16 + (lane & 15);
    baddr[m] = rb * 128 + (((lane >> 4) * 16) ^ ((rb & 7) << 4));
  }

  f32x4 acc[4][4] = {};
  const int c0 = wid * 64 + lane;

  for (int kt = 0; kt < 16; ++kt) {
    const int k0 = kt * 64;
#pragma unroll
    for (int it = 0; it < 4; ++it) {
      int c = it * 256 + c0;              // 16B chunk id, dest byte = c*16
      int row = c >> 3;                   // 128B per row
      int sb = ((((c & 7) << 4)) ^ ((row & 7) << 4)) >> 1;  // inverse-swizzled src elem
      gload16(A    + (size_t)(m0 + row) * NE + k0 + sb, sA + it * 4096 + wid * 1024);
      gload16(Wsel + (size_t)(n0 + row) * NE + k0 + sb, sB + it * 4096 + wid * 1024);
    }
    __syncthreads();
#pragma unroll
    for (int kk = 0; kk < 2; ++kk) {
      s16x8 af[4], bf[4];
#pragma unroll
      for (int m = 0; m < 4; ++m) af[m] = *(const s16x8*)(sA + (aaddr[m] ^ (kk << 6)));
#pragma unroll
      for (int n = 0; n < 4; ++n) bf[n] = *(const s16x8*)(sB + (baddr[n] ^ (kk << 6)));
#pragma unroll
      for (int m = 0; m < 4; ++m)
#pragma unroll
        for (int n = 0; n < 4; ++n)
          acc[m][n] = __builtin_amdgcn_mfma_f32_16x16x32_bf16(af[m], bf[n], acc[m][n], 0, 0, 0);
    }
    __syncthreads();
  }

  // Epilogue. C/D layout: col = lane&15, row = (lane>>4)*4 + reg (m89/m91).
  // Q (which==0) pre-scaled by attn scale*log2e so attn uses exp2 directly.
  const float qsc = (MODE == 0 && ((bx >> 3) == 0)) ? 0.18033688011112042f : 1.0f;
#pragma unroll
  for (int m = 0; m < 4; ++m) {
    const int row0 = m0 + wr + m * 16 + ((lane >> 4) << 2);
#pragma unroll
    for (int n = 0; n < 4; ++n) {
      const int col = n0 + wc + n * 16 + (lane & 15);
      const float bv = bias[col];
      if (MODE == 1) {
#pragma unroll
        for (int r = 0; r < 4; ++r)
          fout[(size_t)(row0 + r) * NE + col] = acc[m][n][r] + bv;
      } else {
        const int b = row0 >> 11;
        const int l = row0 & 2047;
        const int h = col >> 6;
        const int d = col & 63;
        if (which < 2) {
          unsigned short* dst = (which == 0) ? O0 : O1;
#pragma unroll
          for (int r = 0; r < 4; ++r)
            dst[((size_t)(b * NH + h) * NL + (l + r)) * ND + d] = f2b((acc[m][n][r] + bv) * qsc);
        } else {
          // V transposed: [B,H,64,L]; 4 regs are 4 consecutive l -> pack 8B store
          ushort4 pk;
          pk.x = f2b(acc[m][n][0] + bv);
          pk.y = f2b(acc[m][n][1] + bv);
          pk.z = f2b(acc[m][n][2] + bv);
          pk.w = f2b(acc[m][n][3] + bv);
          *(ushort4*)(O2 + ((size_t)(b * NH + h) * ND + d) * NL + l) = pk;
        }
      }
    }
  }
}

// ---------------- flash attention fwd, per (b,h), q-tile 128 ----------------
// Q (pre-scaled), K: [B,H,L,64] bf16; Vt: [B,H,64,L] bf16; AO out: [B,L,E] bf16.
// Swapped QK^T: S^T = mfma(K,Q) -> lane owns one q-row per hi-group.
// kv-tile 64, double-buffered K/V with prefetch-before-compute (T3 2-phase).
__launch_bounds__(256, 3)
__global__ void attn_kernel(const unsigned short* __restrict__ Q,
                            const unsigned short* __restrict__ K,
                            const unsigned short* __restrict__ Vt,
                            unsigned short* __restrict__ AO)
{
  __shared__ alignas(16) char smem[49152];
  // [0,8K)+[8K,16K): sK dbuf [64 kv][64 d]  swizzled
  // [16K,24K)+[24K,32K): sV dbuf [64 d][64 kv] swizzled
  // [32K,48K): sP, per wave 4KB (2 m-tiles x [16 q][64 kv] swizzled)

  const int tid = threadIdx.x;
  const int lane = tid & 63;
  const int wid = tid >> 6;
  const int hi = lane >> 4;
  const int qi = lane & 15;
  const int qt = blockIdx.x;
  const int bh = blockIdx.y;
  const int b = bh >> 4;
  const int h = bh & 15;
  const size_t base = (size_t)bh * NL * ND;
  const int q0 = qt * 128 + wid * 32;     // this wave's 32 q rows

  // Q fragments (B-role) held in registers for the whole kernel
  s16x8 qf[2][2];
#pragma unroll
  for (int m = 0; m < 2; ++m)
#pragma unroll
    for (int kk = 0; kk < 2; ++kk)
      qf[m][kk] = *(const s16x8*)(Q + base + (size_t)(q0 + m * 16 + qi) * ND
                                  + kk * 32 + hi * 8);

  f32x4 o[2][4] = {};                     // o[m][dt]: lane holds O[q][dt*16+hi*4+r]
  float rm[2] = {-1e30f, -1e30f};
  float rl[2] = {0.f, 0.f};

  int kaddr[4], vaddr[4];
#pragma unroll
  for (int n = 0; n < 4; ++n) {
    int rk = n * 16 + qi;
    kaddr[n] = rk * 128 + ((hi * 16) ^ ((rk & 7) << 4));
    vaddr[n] = kaddr[n];                  // same formula (rows x 128B, swizzled)
  }
  char* sP = smem + 32768 + wid * 4096;
  int pwoff[4], proff[2];
#pragma unroll
  for (int n = 0; n < 4; ++n)
    pwoff[n] = qi * 128 + ((n * 32 + hi * 8) ^ ((qi & 7) << 4));
#pragma unroll
  for (int ks = 0; ks < 2; ++ks)
    proff[ks] = qi * 128 + ((ks * 64 + hi * 16) ^ ((qi & 7) << 4));

#define STAGE(T, BUF)                                                          \
  do {                                                                         \
    const int kv0_ = (T) * 64;                                                 \
    char* sKb_ = smem + (BUF) * 8192;                                          \
    char* sVb_ = smem + 16384 + (BUF) * 8192;                                  \
    _Pragma("unroll")                                                          \
    for (int it = 0; it < 2; ++it) {                                           \
      int c = it * 256 + wid * 64 + lane;                                      \
      int row = c >> 3;                                                        \
      int sb = (((c & 7) << 4) ^ ((row & 7) << 4)) >> 1;                       \
      gload16(K  + base + (size_t)(kv0_ + row) * ND + sb,                      \
              sKb_ + it * 4096 + wid * 1024);                                  \
      gload16(Vt + base + (size_t)row * NL + kv0_ + sb,                        \
              sVb_ + it * 4096 + wid * 1024);                                  \
    }                                                                          \
  } while (0)

  STAGE(0, 0);
  __syncthreads();

  for (int t = 0; t < 32; ++t) {
    const int cur = t & 1;
    if (t < 31) STAGE(t + 1, cur ^ 1);
    const char* sKb = smem + cur * 8192;
    const char* sVb = smem + 16384 + cur * 8192;

    // S^T = K Q^T : s[m][n][r] = S[q = q0+m*16+qi][kv = n*16+hi*4+r] (exp2 units)
    f32x4 s[2][4] = {};
#pragma unroll
    for (int kk = 0; kk < 2; ++kk) {
      s16x8 kf[4];
#pragma unroll
      for (int n = 0; n < 4; ++n) kf[n] = *(const s16x8*)(sKb + (kaddr[n] ^ (kk << 6)));
#pragma unroll
      for (int m = 0; m < 2; ++m)
#pragma unroll
        for (int n = 0; n < 4; ++n)
          s[m][n] = __builtin_amdgcn_mfma_f32_16x16x32_bf16(kf[n], qf[m][kk], s[m][n], 0, 0, 0);
    }

    // online softmax: in-lane over 16 vals + 2 shfl across hi-groups
#pragma unroll
    for (int m = 0; m < 2; ++m) {
      float pm = s[m][0][0];
#pragma unroll
      for (int n = 0; n < 4; ++n)
#pragma unroll
        for (int r = 0; r < 4; ++r) pm = fmaxf(pm, s[m][n][r]);
      pm = fmaxf(pm, __shfl_xor(pm, 16));
      pm = fmaxf(pm, __shfl_xor(pm, 32));
      float mn = rm[m];
      if (!__all(pm - mn <= 8.0f)) {      // T13 defer-max
        mn = fmaxf(mn, pm);
        float al = __builtin_amdgcn_exp2f(rm[m] - mn);
        rl[m] *= al;
#pragma unroll
        for (int dt = 0; dt < 4; ++dt) o[m][dt] = o[m][dt] * al;
        rm[m] = mn;
      }
      float ts = 0.f;
#pragma unroll
      for (int n = 0; n < 4; ++n) {
        float p0 = __builtin_amdgcn_exp2f(s[m][n][0] - mn);
        float p1 = __builtin_amdgcn_exp2f(s[m][n][1] - mn);
        float p2 = __builtin_amdgcn_exp2f(s[m][n][2] - mn);
        float p3 = __builtin_amdgcn_exp2f(s[m][n][3] - mn);
        ts += (p0 + p1) + (p2 + p3);
        uint2 w;
        w.x = pk2(p0, p1);
        w.y = pk2(p2, p3);
        *(uint2*)(sP + m * 2048 + pwoff[n]) = w;
      }
      ts += __shfl_xor(ts, 16);
      ts += __shfl_xor(ts, 32);
      rl[m] += ts;
    }

    // O^T += V^T P^T : o[m][dt] = mfma(vf[dt], pf[m], o)
#pragma unroll
    for (int ks = 0; ks < 2; ++ks) {
      s16x8 vf[4];
#pragma unroll
      for (int dt = 0; dt < 4; ++dt) vf[dt] = *(const s16x8*)(sVb + (vaddr[dt] ^ (ks << 6)));
#pragma unroll
      for (int m = 0; m < 2; ++m) {
        s16x8 pf = *(const s16x8*)(sP + m * 2048 + proff[ks]);
#pragma unroll
        for (int dt = 0; dt < 4; ++dt)
          o[m][dt] = __builtin_amdgcn_mfma_f32_16x16x32_bf16(vf[dt], pf, o[m][dt], 0, 0, 0);
      }
    }
    __syncthreads();
  }
#undef STAGE

  // normalize + write [B,L,E] bf16 (8B packed stores)
#pragma unroll
  for (int m = 0; m < 2; ++m) {
    const float inv = 1.0f / rl[m];
    const int qg = q0 + m * 16 + qi;
#pragma unroll
    for (int dt = 0; dt < 4; ++dt) {
      ushort4 pk;
      pk.x = f2b(o[m][dt][0] * inv);
      pk.y = f2b(o[m][dt][1] * inv);
      pk.z = f2b(o[m][dt][2] * inv);
      pk.w = f2b(o[m][dt][3] * inv);
      *(ushort4*)(AO + (size_t)(b * NL + qg) * NE + h * 64 + dt * 16 + hi * 4) = pk;
    }
  }
}

// ---------------------------------------------------------------------------
extern "C" void kernel_launch(void* const* d_in, const int* in_sizes, int n_in,
                              void* d_out, int out_size, void* d_ws, size_t ws_size,
                              hipStream_t stream) {
  const float* x  = (const float*)d_in[0];
  const float* Wq = (const float*)d_in[1];
  const float* bq = (const float*)d_in[2];
  const float* Wk = (const float*)d_in[3];
  const float* bk = (const float*)d_in[4];
  const float* Wv = (const float*)d_in[5];
  const float* bv = (const float*)d_in[6];
  const float* Wo = (const float*)d_in[7];
  const float* bo = (const float*)d_in[8];
  float* out = (float*)d_out;
  char* ws = (char*)d_ws;

  // Workspace layout (72 MB):
  //   [ 0,16) MB : xb  (x bf16)      -- dead after gemm<0>; reused as AOw
  //   [16,18) MB : wqb   [18,20): wkb   [20,22): wvb   [22,24): wob
  //   [24,40) MB : Qw [B,H,L,64] (pre-scaled)
  //   [40,56) MB : Kw [B,H,L,64]
  //   [56,72) MB : Vtw [B,H,64,L]
  unsigned short* xb  = (unsigned short*)(ws);
  unsigned short* AOw = (unsigned short*)(ws);                      // aliases xb
  unsigned short* wqb = (unsigned short*)(ws + (16u << 20));
  unsigned short* wkb = (unsigned short*)(ws + (18u << 20));
  unsigned short* wvb = (unsigned short*)(ws + (20u << 20));
  unsigned short* wob = (unsigned short*)(ws + (22u << 20));
  unsigned short* Qw  = (unsigned short*)(ws + (24u << 20));
  unsigned short* Kw  = (unsigned short*)(ws + (40u << 20));
  unsigned short* Vtw = (unsigned short*)(ws + (56u << 20));
  (void)in_sizes; (void)n_in; (void)out_size; (void)ws_size;

  cvt_kernel<<<1024, 256, 0, stream>>>(x, xb, (NM * NE) / 8);
  cvt4_kernel<<<dim3(128, 4), 256, 0, stream>>>(Wq, Wk, Wv, Wo,
                                                wqb, wkb, wvb, wob, (NE * NE) / 8);

  gemm_bt<0><<<dim3(24, 64), 256, 0, stream>>>(xb, wqb, wkb, wvb, bq, bk, bv,
                                               Qw, Kw, Vtw, nullptr);
  attn_kernel<<<dim3(16, 64), 256, 0, stream>>>(Qw, Kw, Vtw, AOw);
  gemm_bt<1><<<dim3(8, 64), 256, 0, stream>>>(AOw, wob, nullptr, nullptr, bo,
                                              nullptr, nullptr,
                                              nullptr, nullptr, nullptr, out);
}

// Round 5
// 299.397 us; speedup vs baseline: 1.2053x; 1.0476x over previous
//
#include <hip/hip_runtime.h>
#include <hip/hip_bf16.h>
#include <stdint.h>

// Problem constants
#define NB 4
#define NL 2048
#define NE 1024
#define NH 16
#define ND 64
#define NM (NB*NL)   // 8192 rows

typedef float f32x4 __attribute__((ext_vector_type(4)));
typedef short s16x8 __attribute__((ext_vector_type(8)));

__device__ __forceinline__ unsigned short f2b(float f) {
  uint32_t u = __float_as_uint(f);
  u += 0x7fffu + ((u >> 16) & 1u);   // RNE; inputs are finite
  return (unsigned short)(u >> 16);
}

// packed pair via v_cvt_pk_bf16_f32 (compiler-lowered, m240: don't hand-write asm)
__device__ __forceinline__ uint32_t pk2(float a, float b) {
  __hip_bfloat162 h = __float22bfloat162_rn(make_float2(a, b));
  union { __hip_bfloat162 h; uint32_t u; } c; c.h = h; return c.u;
}

__device__ __forceinline__ void gload16(const void* g, void* l) {
  __builtin_amdgcn_global_load_lds((const __attribute__((address_space(1))) void*)g,
                                   (__attribute__((address_space(3))) void*)l, 16, 0, 0);
}

// ---------------- fp32 -> bf16 conversion (vectorized, grid-stride) --------
__global__ void cvt_kernel(const float* __restrict__ in, unsigned short* __restrict__ out, int n8) {
  int stride = gridDim.x * blockDim.x;
  for (int i = blockIdx.x * blockDim.x + threadIdx.x; i < n8; i += stride) {
    const float4* p = (const float4*)in + (size_t)i * 2;
    float4 a = p[0], b = p[1];
    uint4 r;
    r.x = pk2(a.x, a.y); r.y = pk2(a.z, a.w);
    r.z = pk2(b.x, b.y); r.w = pk2(b.z, b.w);
    *((uint4*)out + i) = r;
  }
}

// 4 weight matrices in one launch; blockIdx.y selects the matrix.
__global__ void cvt4_kernel(const float* __restrict__ w0, const float* __restrict__ w1,
                            const float* __restrict__ w2, const float* __restrict__ w3,
                            unsigned short* __restrict__ o0, unsigned short* __restrict__ o1,
                            unsigned short* __restrict__ o2, unsigned short* __restrict__ o3,
                            int n8) {
  const int y = blockIdx.y;
  const float* in = (y == 0) ? w0 : (y == 1) ? w1 : (y == 2) ? w2 : w3;
  unsigned short* out = (y == 0) ? o0 : (y == 1) ? o1 : (y == 2) ? o2 : o3;
  int stride = gridDim.x * blockDim.x;
  for (int i = blockIdx.x * blockDim.x + threadIdx.x; i < n8; i += stride) {
    const float4* p = (const float4*)in + (size_t)i * 2;
    float4 a = p[0], b = p[1];
    uint4 r;
    r.x = pk2(a.x, a.y); r.y = pk2(a.z, a.w);
    r.z = pk2(b.x, b.y); r.w = pk2(b.z, b.w);
    *((uint4*)out + i) = r;
  }
}

// ---------------- B^T-input bf16 GEMM, 128x128 tile, BK=64 -----------------
// C[m][n] = sum_k A[m][k]*W[n][k] + bias[n]
// MODE 0: fused QKV projection. blockIdx.x: 0-7 -> Q, 8-15 -> K, 16-23 -> V.
//         Q,K written [B,H,L,64] bf16 (Q pre-scaled by 0.125*log2e);
//         V written transposed [B,H,64,L] bf16.
// MODE 1: output projection, fp32 out [M][NE] + bias.
template<int MODE>
__launch_bounds__(256, 2)
__global__ void gemm_bt(const unsigned short* __restrict__ A,
                        const unsigned short* __restrict__ W0,
                        const unsigned short* __restrict__ W1,
                        const unsigned short* __restrict__ W2,
                        const float* __restrict__ b0,
                        const float* __restrict__ b1,
                        const float* __restrict__ b2,
                        unsigned short* __restrict__ O0,
                        unsigned short* __restrict__ O1,
                        unsigned short* __restrict__ O2,
                        float* __restrict__ fout)
{
  __shared__ alignas(16) char smem[32768];
  char* sA = smem;            // [128][64] bf16, XOR-swizzled
  char* sB = smem + 16384;    // [128][64] bf16, XOR-swizzled

  const int tid = threadIdx.x;
  const int lane = tid & 63;
  const int wid = tid >> 6;
  const int bx = blockIdx.x, by = blockIdx.y;
  const int m0 = by * 128;

  int which = 0;
  const unsigned short* Wsel;
  const float* bias;
  int n0;
  if (MODE == 0) {
    which = bx >> 3;
    Wsel = (which == 0) ? W0 : ((which == 1) ? W1 : W2);
    bias = (which == 0) ? b0 : ((which == 1) ? b1 : b2);
    n0 = (bx & 7) * 128;
  } else {
    Wsel = W0; bias = b0; n0 = bx * 128;
  }

  const int wr = (wid >> 1) * 64;
  const int wc = (wid & 1) * 64;
  int aaddr[4], baddr[4];
#pragma unroll
  for (int m = 0; m < 4; ++m) {
    int ra = wr + m * 16 + (lane & 15);
    aaddr[m] = ra * 128 + (((lane >> 4) * 16) ^ ((ra & 7) << 4));
    int rb = wc + m * 16 + (lane & 15);
    baddr[m] = rb * 128 + (((lane >> 4) * 16) ^ ((rb & 7) << 4));
  }

  f32x4 acc[4][4] = {};
  const int c0 = wid * 64 + lane;

  for (int kt = 0; kt < 16; ++kt) {
    const int k0 = kt * 64;
#pragma unroll
    for (int it = 0; it < 4; ++it) {
      int c = it * 256 + c0;              // 16B chunk id, dest byte = c*16
      int row = c >> 3;                   // 128B per row
      int sb = ((((c & 7) << 4)) ^ ((row & 7) << 4)) >> 1;  // inverse-swizzled src elem
      gload16(A    + (size_t)(m0 + row) * NE + k0 + sb, sA + it * 4096 + wid * 1024);
      gload16(Wsel + (size_t)(n0 + row) * NE + k0 + sb, sB + it * 4096 + wid * 1024);
    }
    __syncthreads();
#pragma unroll
    for (int kk = 0; kk < 2; ++kk) {
      s16x8 af[4], bf[4];
#pragma unroll
      for (int m = 0; m < 4; ++m) af[m] = *(const s16x8*)(sA + (aaddr[m] ^ (kk << 6)));
#pragma unroll
      for (int n = 0; n < 4; ++n) bf[n] = *(const s16x8*)(sB + (baddr[n] ^ (kk << 6)));
#pragma unroll
      for (int m = 0; m < 4; ++m)
#pragma unroll
        for (int n = 0; n < 4; ++n)
          acc[m][n] = __builtin_amdgcn_mfma_f32_16x16x32_bf16(af[m], bf[n], acc[m][n], 0, 0, 0);
    }
    __syncthreads();
  }

  // Epilogue. C/D layout: col = lane&15, row = (lane>>4)*4 + reg (m89/m91).
  // Q (which==0) pre-scaled by attn scale*log2e so attn uses exp2 directly.
  const float qsc = (MODE == 0 && ((bx >> 3) == 0)) ? 0.18033688011112042f : 1.0f;
#pragma unroll
  for (int m = 0; m < 4; ++m) {
    const int row0 = m0 + wr + m * 16 + ((lane >> 4) << 2);
#pragma unroll
    for (int n = 0; n < 4; ++n) {
      const int col = n0 + wc + n * 16 + (lane & 15);
      const float bv = bias[col];
      if (MODE == 1) {
#pragma unroll
        for (int r = 0; r < 4; ++r)
          fout[(size_t)(row0 + r) * NE + col] = acc[m][n][r] + bv;
      } else {
        const int b = row0 >> 11;
        const int l = row0 & 2047;
        const int h = col >> 6;
        const int d = col & 63;
        if (which < 2) {
          unsigned short* dst = (which == 0) ? O0 : O1;
#pragma unroll
          for (int r = 0; r < 4; ++r)
            dst[((size_t)(b * NH + h) * NL + (l + r)) * ND + d] = f2b((acc[m][n][r] + bv) * qsc);
        } else {
          // V transposed: [B,H,64,L]; 4 regs are 4 consecutive l -> pack 8B store
          uint2 w;
          w.x = pk2(acc[m][n][0] + bv, acc[m][n][1] + bv);
          w.y = pk2(acc[m][n][2] + bv, acc[m][n][3] + bv);
          *(uint2*)(O2 + ((size_t)(b * NH + h) * ND + d) * NL + l) = w;
        }
      }
    }
  }
}

// ---------------- flash attention fwd, per (b,h), q-tile 128 ----------------
// Q (pre-scaled), K: [B,H,L,64] bf16; Vt: [B,H,64,L] bf16; AO out: [B,L,E] bf16.
// Swapped QK^T: S^T = mfma(K,Q) -> lane owns one q-row per hi-group.
// kv-tile 64, double-buffered K/V with prefetch-before-compute (T3 2-phase).
__launch_bounds__(256, 3)
__global__ void attn_kernel(const unsigned short* __restrict__ Q,
                            const unsigned short* __restrict__ K,
                            const unsigned short* __restrict__ Vt,
                            unsigned short* __restrict__ AO)
{
  __shared__ alignas(16) char smem[49152];
  // [0,8K)+[8K,16K): sK dbuf [64 kv][64 d]  swizzled
  // [16K,24K)+[24K,32K): sV dbuf [64 d][64 kv] swizzled
  // [32K,48K): sP, per wave 4KB (2 m-tiles x [16 q][64 kv] swizzled)

  const int tid = threadIdx.x;
  const int lane = tid & 63;
  const int wid = tid >> 6;
  const int hi = lane >> 4;
  const int qi = lane & 15;
  const int qt = blockIdx.x;
  const int bh = blockIdx.y;
  const int b = bh >> 4;
  const int h = bh & 15;
  const size_t base = (size_t)bh * NL * ND;
  const int q0 = qt * 128 + wid * 32;     // this wave's 32 q rows

  // Q fragments (B-role) held in registers for the whole kernel
  s16x8 qf[2][2];
#pragma unroll
  for (int m = 0; m < 2; ++m)
#pragma unroll
    for (int kk = 0; kk < 2; ++kk)
      qf[m][kk] = *(const s16x8*)(Q + base + (size_t)(q0 + m * 16 + qi) * ND
                                  + kk * 32 + hi * 8);

  f32x4 o[2][4] = {};                     // o[m][dt]: lane holds O[q][dt*16+hi*4+r]
  float rm[2] = {-1e30f, -1e30f};
  float rl[2] = {0.f, 0.f};

  int kaddr[4], vaddr[4];
#pragma unroll
  for (int n = 0; n < 4; ++n) {
    int rk = n * 16 + qi;
    kaddr[n] = rk * 128 + ((hi * 16) ^ ((rk & 7) << 4));
    vaddr[n] = kaddr[n];                  // same formula (rows x 128B, swizzled)
  }
  char* sP = smem + 32768 + wid * 4096;
  int pwoff[4], proff[2];
#pragma unroll
  for (int n = 0; n < 4; ++n)
    pwoff[n] = qi * 128 + ((n * 32 + hi * 8) ^ ((qi & 7) << 4));
#pragma unroll
  for (int ks = 0; ks < 2; ++ks)
    proff[ks] = qi * 128 + ((ks * 64 + hi * 16) ^ ((qi & 7) << 4));

#define STAGE(T, BUF)                                                          \
  do {                                                                         \
    const int kv0_ = (T) * 64;                                                 \
    char* sKb_ = smem + (BUF) * 8192;                                          \
    char* sVb_ = smem + 16384 + (BUF) * 8192;                                  \
    _Pragma("unroll")                                                          \
    for (int it = 0; it < 2; ++it) {                                           \
      int c = it * 256 + wid * 64 + lane;                                      \
      int row = c >> 3;                                                        \
      int sb = (((c & 7) << 4) ^ ((row & 7) << 4)) >> 1;                       \
      gload16(K  + base + (size_t)(kv0_ + row) * ND + sb,                      \
              sKb_ + it * 4096 + wid * 1024);                                  \
      gload16(Vt + base + (size_t)row * NL + kv0_ + sb,                        \
              sVb_ + it * 4096 + wid * 1024);                                  \
    }                                                                          \
  } while (0)

  STAGE(0, 0);
  __syncthreads();

  for (int t = 0; t < 32; ++t) {
    const int cur = t & 1;
    if (t < 31) STAGE(t + 1, cur ^ 1);
    const char* sKb = smem + cur * 8192;
    const char* sVb = smem + 16384 + cur * 8192;

    // S^T = K Q^T : s[m][n][r] = S[q = q0+m*16+qi][kv = n*16+hi*4+r] (exp2 units)
    f32x4 s[2][4] = {};
    __builtin_amdgcn_s_setprio(1);
#pragma unroll
    for (int kk = 0; kk < 2; ++kk) {
      s16x8 kf[4];
#pragma unroll
      for (int n = 0; n < 4; ++n) kf[n] = *(const s16x8*)(sKb + (kaddr[n] ^ (kk << 6)));
#pragma unroll
      for (int m = 0; m < 2; ++m)
#pragma unroll
        for (int n = 0; n < 4; ++n)
          s[m][n] = __builtin_amdgcn_mfma_f32_16x16x32_bf16(kf[n], qf[m][kk], s[m][n], 0, 0, 0);
    }
    __builtin_amdgcn_s_setprio(0);

    // online softmax: in-lane tree over 16 vals (max3-fusable) + 2 shfl
#pragma unroll
    for (int m = 0; m < 2; ++m) {
      float a0 = fmaxf(fmaxf(fmaxf(s[m][0][0], s[m][0][1]), s[m][0][2]), s[m][0][3]);
      float a1 = fmaxf(fmaxf(fmaxf(s[m][1][0], s[m][1][1]), s[m][1][2]), s[m][1][3]);
      float a2 = fmaxf(fmaxf(fmaxf(s[m][2][0], s[m][2][1]), s[m][2][2]), s[m][2][3]);
      float a3 = fmaxf(fmaxf(fmaxf(s[m][3][0], s[m][3][1]), s[m][3][2]), s[m][3][3]);
      float pm = fmaxf(fmaxf(a0, a1), fmaxf(a2, a3));
      pm = fmaxf(pm, __shfl_xor(pm, 16));
      pm = fmaxf(pm, __shfl_xor(pm, 32));
      float mn = rm[m];
      if (!__all(pm - mn <= 8.0f)) {      // T13 defer-max
        mn = fmaxf(mn, pm);
        float al = __builtin_amdgcn_exp2f(rm[m] - mn);
        rl[m] *= al;
#pragma unroll
        for (int dt = 0; dt < 4; ++dt) o[m][dt] = o[m][dt] * al;
        rm[m] = mn;
      }
      float ts = 0.f;
#pragma unroll
      for (int n = 0; n < 4; ++n) {
        float p0 = __builtin_amdgcn_exp2f(s[m][n][0] - mn);
        float p1 = __builtin_amdgcn_exp2f(s[m][n][1] - mn);
        float p2 = __builtin_amdgcn_exp2f(s[m][n][2] - mn);
        float p3 = __builtin_amdgcn_exp2f(s[m][n][3] - mn);
        ts += (p0 + p1) + (p2 + p3);
        uint2 w;
        w.x = pk2(p0, p1);
        w.y = pk2(p2, p3);
        *(uint2*)(sP + m * 2048 + pwoff[n]) = w;
      }
      ts += __shfl_xor(ts, 16);
      ts += __shfl_xor(ts, 32);
      rl[m] += ts;
    }

    // O^T += V^T P^T : o[m][dt] = mfma(vf[dt], pf[m], o)
    __builtin_amdgcn_s_setprio(1);
#pragma unroll
    for (int ks = 0; ks < 2; ++ks) {
      s16x8 vf[4];
#pragma unroll
      for (int dt = 0; dt < 4; ++dt) vf[dt] = *(const s16x8*)(sVb + (vaddr[dt] ^ (ks << 6)));
#pragma unroll
      for (int m = 0; m < 2; ++m) {
        s16x8 pf = *(const s16x8*)(sP + m * 2048 + proff[ks]);
#pragma unroll
        for (int dt = 0; dt < 4; ++dt)
          o[m][dt] = __builtin_amdgcn_mfma_f32_16x16x32_bf16(vf[dt], pf, o[m][dt], 0, 0, 0);
      }
    }
    __builtin_amdgcn_s_setprio(0);
    __syncthreads();
  }
#undef STAGE

  // normalize + write [B,L,E] bf16 (8B packed stores)
#pragma unroll
  for (int m = 0; m < 2; ++m) {
    const float inv = 1.0f / rl[m];
    const int qg = q0 + m * 16 + qi;
#pragma unroll
    for (int dt = 0; dt < 4; ++dt) {
      uint2 w;
      w.x = pk2(o[m][dt][0] * inv, o[m][dt][1] * inv);
      w.y = pk2(o[m][dt][2] * inv, o[m][dt][3] * inv);
      *(uint2*)(AO + (size_t)(b * NL + qg) * NE + h * 64 + dt * 16 + hi * 4) = w;
    }
  }
}

// ---------------------------------------------------------------------------
extern "C" void kernel_launch(void* const* d_in, const int* in_sizes, int n_in,
                              void* d_out, int out_size, void* d_ws, size_t ws_size,
                              hipStream_t stream) {
  const float* x  = (const float*)d_in[0];
  const float* Wq = (const float*)d_in[1];
  const float* bq = (const float*)d_in[2];
  const float* Wk = (const float*)d_in[3];
  const float* bk = (const float*)d_in[4];
  const float* Wv = (const float*)d_in[5];
  const float* bv = (const float*)d_in[6];
  const float* Wo = (const float*)d_in[7];
  const float* bo = (const float*)d_in[8];
  float* out = (float*)d_out;
  char* ws = (char*)d_ws;

  // Workspace layout (72 MB):
  //   [ 0,16) MB : xb  (x bf16)      -- dead after gemm<0>; reused as AOw
  //   [16,18) MB : wqb   [18,20): wkb   [20,22): wvb   [22,24): wob
  //   [24,40) MB : Qw [B,H,L,64] (pre-scaled)
  //   [40,56) MB : Kw [B,H,L,64]
  //   [56,72) MB : Vtw [B,H,64,L]
  unsigned short* xb  = (unsigned short*)(ws);
  unsigned short* AOw = (unsigned short*)(ws);                      // aliases xb
  unsigned short* wqb = (unsigned short*)(ws + (16u << 20));
  unsigned short* wkb = (unsigned short*)(ws + (18u << 20));
  unsigned short* wvb = (unsigned short*)(ws + (20u << 20));
  unsigned short* wob = (unsigned short*)(ws + (22u << 20));
  unsigned short* Qw  = (unsigned short*)(ws + (24u << 20));
  unsigned short* Kw  = (unsigned short*)(ws + (40u << 20));
  unsigned short* Vtw = (unsigned short*)(ws + (56u << 20));
  (void)in_sizes; (void)n_in; (void)out_size; (void)ws_size;

  cvt_kernel<<<1024, 256, 0, stream>>>(x, xb, (NM * NE) / 8);
  cvt4_kernel<<<dim3(128, 4), 256, 0, stream>>>(Wq, Wk, Wv, Wo,
                                                wqb, wkb, wvb, wob, (NE * NE) / 8);

  gemm_bt<0><<<dim3(24, 64), 256, 0, stream>>>(xb, wqb, wkb, wvb, bq, bk, bv,
                                               Qw, Kw, Vtw, nullptr);
  attn_kernel<<<dim3(16, 64), 256, 0, stream>>>(Qw, Kw, Vtw, AOw);
  gemm_bt<1><<<dim3(8, 64), 256, 0, stream>>>(AOw, wob, nullptr, nullptr, bo,
                                              nullptr, nullptr,
                                              nullptr, nullptr, nullptr, out);
}

// Round 6
// 298.492 us; speedup vs baseline: 1.2089x; 1.0030x over previous
//
#include <hip/hip_runtime.h>
#include <hip/hip_bf16.h>
#include <stdint.h>

// Problem constants
#define NB 4
#define NL 2048
#define NE 1024
#define NH 16
#define ND 64
#define NM (NB*NL)   // 8192 rows

typedef float f32x4 __attribute__((ext_vector_type(4)));
typedef float f32x16 __attribute__((ext_vector_type(16)));
typedef short s16x8 __attribute__((ext_vector_type(8)));
typedef unsigned int u32x4 __attribute__((ext_vector_type(4)));

__device__ __forceinline__ unsigned short f2b(float f) {
  uint32_t u = __float_as_uint(f);
  u += 0x7fffu + ((u >> 16) & 1u);   // RNE; inputs are finite
  return (unsigned short)(u >> 16);
}

// packed pair via v_cvt_pk_bf16_f32 (compiler-lowered, m240: don't hand-write asm)
__device__ __forceinline__ uint32_t pk2(float a, float b) {
  __hip_bfloat162 h = __float22bfloat162_rn(make_float2(a, b));
  union { __hip_bfloat162 h; uint32_t u; } c; c.h = h; return c.u;
}

__device__ __forceinline__ void gload16(const void* g, void* l) {
  __builtin_amdgcn_global_load_lds((const __attribute__((address_space(1))) void*)g,
                                   (__attribute__((address_space(3))) void*)l, 16, 0, 0);
}

// ---------------- fp32 -> bf16 conversion (vectorized, grid-stride) --------
__global__ void cvt_kernel(const float* __restrict__ in, unsigned short* __restrict__ out, int n8) {
  int stride = gridDim.x * blockDim.x;
  for (int i = blockIdx.x * blockDim.x + threadIdx.x; i < n8; i += stride) {
    const float4* p = (const float4*)in + (size_t)i * 2;
    float4 a = p[0], b = p[1];
    uint4 r;
    r.x = pk2(a.x, a.y); r.y = pk2(a.z, a.w);
    r.z = pk2(b.x, b.y); r.w = pk2(b.z, b.w);
    *((uint4*)out + i) = r;
  }
}

// 4 weight matrices in one launch; blockIdx.y selects the matrix.
__global__ void cvt4_kernel(const float* __restrict__ w0, const float* __restrict__ w1,
                            const float* __restrict__ w2, const float* __restrict__ w3,
                            unsigned short* __restrict__ o0, unsigned short* __restrict__ o1,
                            unsigned short* __restrict__ o2, unsigned short* __restrict__ o3,
                            int n8) {
  const int y = blockIdx.y;
  const float* in = (y == 0) ? w0 : (y == 1) ? w1 : (y == 2) ? w2 : w3;
  unsigned short* out = (y == 0) ? o0 : (y == 1) ? o1 : (y == 2) ? o2 : o3;
  int stride = gridDim.x * blockDim.x;
  for (int i = blockIdx.x * blockDim.x + threadIdx.x; i < n8; i += stride) {
    const float4* p = (const float4*)in + (size_t)i * 2;
    float4 a = p[0], b = p[1];
    uint4 r;
    r.x = pk2(a.x, a.y); r.y = pk2(a.z, a.w);
    r.z = pk2(b.x, b.y); r.w = pk2(b.z, b.w);
    *((uint4*)out + i) = r;
  }
}

// ---------------- B^T-input bf16 GEMM, 128x128 tile, BK=64 -----------------
// C[m][n] = sum_k A[m][k]*W[n][k] + bias[n]
// MODE 0: fused QKV projection. blockIdx.x: 0-7 -> Q, 8-15 -> K, 16-23 -> V.
//         Q,K written [B,H,L,64] bf16 (Q pre-scaled by 0.125*log2e);
//         V written transposed [B,H,64,L] bf16.
// MODE 1: output projection, fp32 out [M][NE] + bias.
template<int MODE>
__launch_bounds__(256, 2)
__global__ void gemm_bt(const unsigned short* __restrict__ A,
                        const unsigned short* __restrict__ W0,
                        const unsigned short* __restrict__ W1,
                        const unsigned short* __restrict__ W2,
                        const float* __restrict__ b0,
                        const float* __restrict__ b1,
                        const float* __restrict__ b2,
                        unsigned short* __restrict__ O0,
                        unsigned short* __restrict__ O1,
                        unsigned short* __restrict__ O2,
                        float* __restrict__ fout)
{
  __shared__ alignas(16) char smem[32768];
  char* sA = smem;            // [128][64] bf16, XOR-swizzled
  char* sB = smem + 16384;    // [128][64] bf16, XOR-swizzled

  const int tid = threadIdx.x;
  const int lane = tid & 63;
  const int wid = tid >> 6;
  const int bx = blockIdx.x, by = blockIdx.y;
  const int m0 = by * 128;

  int which = 0;
  const unsigned short* Wsel;
  const float* bias;
  int n0;
  if (MODE == 0) {
    which = bx >> 3;
    Wsel = (which == 0) ? W0 : ((which == 1) ? W1 : W2);
    bias = (which == 0) ? b0 : ((which == 1) ? b1 : b2);
    n0 = (bx & 7) * 128;
  } else {
    Wsel = W0; bias = b0; n0 = bx * 128;
  }

  const int wr = (wid >> 1) * 64;
  const int wc = (wid & 1) * 64;
  int aaddr[4], baddr[4];
#pragma unroll
  for (int m = 0; m < 4; ++m) {
    int ra = wr + m * 16 + (lane & 15);
    aaddr[m] = ra * 128 + (((lane >> 4) * 16) ^ ((ra & 7) << 4));
    int rb = wc + m * 16 + (lane & 15);
    baddr[m] = rb * 128 + (((lane >> 4) * 16) ^ ((rb & 7) << 4));
  }

  f32x4 acc[4][4] = {};
  const int c0 = wid * 64 + lane;

  for (int kt = 0; kt < 16; ++kt) {
    const int k0 = kt * 64;
#pragma unroll
    for (int it = 0; it < 4; ++it) {
      int c = it * 256 + c0;              // 16B chunk id, dest byte = c*16
      int row = c >> 3;                   // 128B per row
      int sb = ((((c & 7) << 4)) ^ ((row & 7) << 4)) >> 1;  // inverse-swizzled src elem
      gload16(A    + (size_t)(m0 + row) * NE + k0 + sb, sA + it * 4096 + wid * 1024);
      gload16(Wsel + (size_t)(n0 + row) * NE + k0 + sb, sB + it * 4096 + wid * 1024);
    }
    __syncthreads();
#pragma unroll
    for (int kk = 0; kk < 2; ++kk) {
      s16x8 af[4], bf[4];
#pragma unroll
      for (int m = 0; m < 4; ++m) af[m] = *(const s16x8*)(sA + (aaddr[m] ^ (kk << 6)));
#pragma unroll
      for (int n = 0; n < 4; ++n) bf[n] = *(const s16x8*)(sB + (baddr[n] ^ (kk << 6)));
#pragma unroll
      for (int m = 0; m < 4; ++m)
#pragma unroll
        for (int n = 0; n < 4; ++n)
          acc[m][n] = __builtin_amdgcn_mfma_f32_16x16x32_bf16(af[m], bf[n], acc[m][n], 0, 0, 0);
    }
    __syncthreads();
  }

  // Epilogue. C/D layout: col = lane&15, row = (lane>>4)*4 + reg (m89/m91).
  // Q (which==0) pre-scaled by attn scale*log2e so attn uses exp2 directly.
  const float qsc = (MODE == 0 && ((bx >> 3) == 0)) ? 0.18033688011112042f : 1.0f;
#pragma unroll
  for (int m = 0; m < 4; ++m) {
    const int row0 = m0 + wr + m * 16 + ((lane >> 4) << 2);
#pragma unroll
    for (int n = 0; n < 4; ++n) {
      const int col = n0 + wc + n * 16 + (lane & 15);
      const float bv = bias[col];
      if (MODE == 1) {
#pragma unroll
        for (int r = 0; r < 4; ++r)
          fout[(size_t)(row0 + r) * NE + col] = acc[m][n][r] + bv;
      } else {
        const int b = row0 >> 11;
        const int l = row0 & 2047;
        const int h = col >> 6;
        const int d = col & 63;
        if (which < 2) {
          unsigned short* dst = (which == 0) ? O0 : O1;
#pragma unroll
          for (int r = 0; r < 4; ++r)
            dst[((size_t)(b * NH + h) * NL + (l + r)) * ND + d] = f2b((acc[m][n][r] + bv) * qsc);
        } else {
          // V transposed: [B,H,64,L]; 4 regs are 4 consecutive l -> pack 8B store
          uint2 w;
          w.x = pk2(acc[m][n][0] + bv, acc[m][n][1] + bv);
          w.y = pk2(acc[m][n][2] + bv, acc[m][n][3] + bv);
          *(uint2*)(O2 + ((size_t)(b * NH + h) * ND + d) * NL + l) = w;
        }
      }
    }
  }
}

// ---------------- flash attention fwd, per (b,h), q-tile 128 ----------------
// Q (pre-scaled), K: [B,H,L,64] bf16; Vt: [B,H,64,L] bf16; AO out: [B,L,E] bf16.
// 32x32x16 MFMA structure: lane owns q = lane&31; row data split only across
// the lane^32 partner -> in-register P via shfl_xor(32) + selects (T12).
// kv-tile 64, double-buffered K/V, prefetch-before-compute (T3 2-phase).
__launch_bounds__(256, 4)
__global__ void attn_kernel(const unsigned short* __restrict__ Q,
                            const unsigned short* __restrict__ K,
                            const unsigned short* __restrict__ Vt,
                            unsigned short* __restrict__ AO)
{
  __shared__ alignas(16) char smem[32768];
  // [0,8K)+[8K,16K): sK dbuf [64 kv][64 d]  swizzled
  // [16K,24K)+[24K,32K): sV dbuf [64 d][64 kv] swizzled

  const int tid = threadIdx.x;
  const int lane = tid & 63;
  const int wid = tid >> 6;
  const int ql = lane & 31;     // q-row within wave tile (also kv/d row for frags)
  const int hh = lane >> 5;     // half-select (0/1)
  const int qt = blockIdx.x;
  const int bh = blockIdx.y;
  const int b = bh >> 4;
  const int h = bh & 15;
  const size_t base = (size_t)bh * NL * ND;
  const int q0 = qt * 128 + wid * 32;     // this wave's 32 q rows

  // Q fragments (B-role of 32x32x16): lane holds Q[q0+ql][ks*16 + hh*8 + j]
  s16x8 qf[4];
#pragma unroll
  for (int ks = 0; ks < 4; ++ks)
    qf[ks] = *(const s16x8*)(Q + base + (size_t)(q0 + ql) * ND + ks * 16 + hh * 8);

  // fragment LDS byte offsets (same geometry for sK and sV: [64 rows][128B])
  int fa[2][4];
#pragma unroll
  for (int t = 0; t < 2; ++t)
#pragma unroll
    for (int ks = 0; ks < 4; ++ks) {
      int r = t * 32 + ql;
      fa[t][ks] = r * 128 + ((ks * 32 + hh * 16) ^ ((r & 7) << 4));
    }

  f32x16 o0 = {}, o1 = {};      // O^T acc: d = td*32 + 4*hh + (reg&3) + 8*(reg>>2), q = ql
  float rm = -1e30f, rl = 0.f;

#define STAGE(T, BUF)                                                          \
  do {                                                                         \
    const int kv0_ = (T) * 64;                                                 \
    char* sKb_ = smem + (BUF) * 8192;                                          \
    char* sVb_ = smem + 16384 + (BUF) * 8192;                                  \
    _Pragma("unroll")                                                          \
    for (int it = 0; it < 2; ++it) {                                           \
      int c = it * 256 + wid * 64 + lane;                                      \
      int row = c >> 3;                                                        \
      int sb = (((c & 7) << 4) ^ ((row & 7) << 4)) >> 1;                       \
      gload16(K  + base + (size_t)(kv0_ + row) * ND + sb,                      \
              sKb_ + it * 4096 + wid * 1024);                                  \
      gload16(Vt + base + (size_t)row * NL + kv0_ + sb,                        \
              sVb_ + it * 4096 + wid * 1024);                                  \
    }                                                                          \
  } while (0)

  STAGE(0, 0);
  __syncthreads();

  for (int t = 0; t < 32; ++t) {
    const int cur = t & 1;
    if (t < 31) STAGE(t + 1, cur ^ 1);
    const char* sKb = smem + cur * 8192;
    const char* sVb = smem + 16384 + cur * 8192;

    // S^T = K Q^T (two 32-kv halves). s*[reg] = S[q=ql][kv = t32*32+4hh+(reg&3)+8(reg>>2)]
    f32x16 s0 = {}, s1 = {};
    __builtin_amdgcn_s_setprio(1);
#pragma unroll
    for (int ks = 0; ks < 4; ++ks) {
      s16x8 kf0 = *(const s16x8*)(sKb + fa[0][ks]);
      s16x8 kf1 = *(const s16x8*)(sKb + fa[1][ks]);
      s0 = __builtin_amdgcn_mfma_f32_32x32x16_bf16(kf0, qf[ks], s0, 0, 0, 0);
      s1 = __builtin_amdgcn_mfma_f32_32x32x16_bf16(kf1, qf[ks], s1, 0, 0, 0);
    }
    __builtin_amdgcn_s_setprio(0);

    // row max: in-lane tree (32 vals) + partner
    float q0m = fmaxf(fmaxf(s0[0], s0[1]), fmaxf(s0[2], s0[3]));
    float q1m = fmaxf(fmaxf(s0[4], s0[5]), fmaxf(s0[6], s0[7]));
    float q2m = fmaxf(fmaxf(s0[8], s0[9]), fmaxf(s0[10], s0[11]));
    float q3m = fmaxf(fmaxf(s0[12], s0[13]), fmaxf(s0[14], s0[15]));
    float q4m = fmaxf(fmaxf(s1[0], s1[1]), fmaxf(s1[2], s1[3]));
    float q5m = fmaxf(fmaxf(s1[4], s1[5]), fmaxf(s1[6], s1[7]));
    float q6m = fmaxf(fmaxf(s1[8], s1[9]), fmaxf(s1[10], s1[11]));
    float q7m = fmaxf(fmaxf(s1[12], s1[13]), fmaxf(s1[14], s1[15]));
    float pm = fmaxf(fmaxf(fmaxf(q0m, q1m), fmaxf(q2m, q3m)),
                     fmaxf(fmaxf(q4m, q5m), fmaxf(q6m, q7m)));
    pm = fmaxf(pm, __shfl_xor(pm, 32));

    float mn = rm;
    if (!__all(pm - mn <= 8.0f)) {      // T13 defer-max
      mn = fmaxf(mn, pm);
      float al = __builtin_amdgcn_exp2f(rm - mn);
      rl *= al;
      o0 = o0 * al;
      o1 = o1 * al;
      rm = mn;
    }

    // exp + pack to bf16 pairs. w[t][i] = pk2(p[2i], p[2i+1])
    uint32_t w0[8], w1[8];
    float ts0 = 0.f, ts1 = 0.f, ts2 = 0.f, ts3 = 0.f;
#pragma unroll
    for (int i = 0; i < 8; ++i) {
      float e0 = __builtin_amdgcn_exp2f(s0[2 * i]     - mn);
      float e1 = __builtin_amdgcn_exp2f(s0[2 * i + 1] - mn);
      float e2 = __builtin_amdgcn_exp2f(s1[2 * i]     - mn);
      float e3 = __builtin_amdgcn_exp2f(s1[2 * i + 1] - mn);
      ts0 += e0; ts1 += e1; ts2 += e2; ts3 += e3;
      w0[i] = pk2(e0, e1);
      w1[i] = pk2(e2, e3);
    }
    float ts = (ts0 + ts1) + (ts2 + ts3);
    ts += __shfl_xor(ts, 32);
    rl += ts;

    // in-register P exchange across lane^32 (robust shfl+select form).
    // pf[ks] covers kv rows ks*16 + hh*8 + j  (B-frag of PV).
    s16x8 pfr[4];
#pragma unroll
    for (int tt = 0; tt < 2; ++tt) {
      const uint32_t* w = tt ? w1 : w0;
      u32x4 lo, hi;   // lo -> pf[2tt], hi -> pf[2tt+1]
#pragma unroll
      for (int aa = 0; aa < 2; ++aa) {            // a = aa (slots aa, aa+2), low ks
        uint32_t v  = hh ? w[aa] : w[aa + 2];
        uint32_t sv = (uint32_t)__shfl_xor((int)v, 32);
        lo[aa]     = hh ? sv        : w[aa];
        lo[aa + 2] = hh ? w[aa + 2] : sv;
      }
#pragma unroll
      for (int aa = 0; aa < 2; ++aa) {            // a = aa+4 (slots aa, aa+2), high ks
        uint32_t v  = hh ? w[aa + 4] : w[aa + 6];
        uint32_t sv = (uint32_t)__shfl_xor((int)v, 32);
        hi[aa]     = hh ? sv        : w[aa + 4];
        hi[aa + 2] = hh ? w[aa + 6] : sv;
      }
      pfr[2 * tt]     = __builtin_bit_cast(s16x8, lo);
      pfr[2 * tt + 1] = __builtin_bit_cast(s16x8, hi);
    }

    // O^T += V^T P^T
    __builtin_amdgcn_s_setprio(1);
#pragma unroll
    for (int ks = 0; ks < 4; ++ks) {
      s16x8 vf0 = *(const s16x8*)(sVb + fa[0][ks]);
      s16x8 vf1 = *(const s16x8*)(sVb + fa[1][ks]);
      o0 = __builtin_amdgcn_mfma_f32_32x32x16_bf16(vf0, pfr[ks], o0, 0, 0, 0);
      o1 = __builtin_amdgcn_mfma_f32_32x32x16_bf16(vf1, pfr[ks], o1, 0, 0, 0);
    }
    __builtin_amdgcn_s_setprio(0);
    __syncthreads();
  }
#undef STAGE

  // normalize + write [B,L,E] bf16 (8B packed stores)
  const float inv = 1.0f / rl;
  const size_t orow = (size_t)(b * NL + q0 + ql) * NE + h * 64;
#pragma unroll
  for (int q4 = 0; q4 < 4; ++q4) {
    uint2 wv;
    wv.x = pk2(o0[4 * q4] * inv, o0[4 * q4 + 1] * inv);
    wv.y = pk2(o0[4 * q4 + 2] * inv, o0[4 * q4 + 3] * inv);
    *(uint2*)(AO + orow + 4 * hh + 8 * q4) = wv;
  }
#pragma unroll
  for (int q4 = 0; q4 < 4; ++q4) {
    uint2 wv;
    wv.x = pk2(o1[4 * q4] * inv, o1[4 * q4 + 1] * inv);
    wv.y = pk2(o1[4 * q4 + 2] * inv, o1[4 * q4 + 3] * inv);
    *(uint2*)(AO + orow + 32 + 4 * hh + 8 * q4) = wv;
  }
}

// ---------------------------------------------------------------------------
extern "C" void kernel_launch(void* const* d_in, const int* in_sizes, int n_in,
                              void* d_out, int out_size, void* d_ws, size_t ws_size,
                              hipStream_t stream) {
  const float* x  = (const float*)d_in[0];
  const float* Wq = (const float*)d_in[1];
  const float* bq = (const float*)d_in[2];
  const float* Wk = (const float*)d_in[3];
  const float* bk = (const float*)d_in[4];
  const float* Wv = (const float*)d_in[5];
  const float* bv = (const float*)d_in[6];
  const float* Wo = (const float*)d_in[7];
  const float* bo = (const float*)d_in[8];
  float* out = (float*)d_out;
  char* ws = (char*)d_ws;

  // Workspace layout (72 MB):
  //   [ 0,16) MB : xb  (x bf16)      -- dead after gemm<0>; reused as AOw
  //   [16,18) MB : wqb   [18,20): wkb   [20,22): wvb   [22,24): wob
  //   [24,40) MB : Qw [B,H,L,64] (pre-scaled)
  //   [40,56) MB : Kw [B,H,L,64]
  //   [56,72) MB : Vtw [B,H,64,L]
  unsigned short* xb  = (unsigned short*)(ws);
  unsigned short* AOw = (unsigned short*)(ws);                      // aliases xb
  unsigned short* wqb = (unsigned short*)(ws + (16u << 20));
  unsigned short* wkb = (unsigned short*)(ws + (18u << 20));
  unsigned short* wvb = (unsigned short*)(ws + (20u << 20));
  unsigned short* wob = (unsigned short*)(ws + (22u << 20));
  unsigned short* Qw  = (unsigned short*)(ws + (24u << 20));
  unsigned short* Kw  = (unsigned short*)(ws + (40u << 20));
  unsigned short* Vtw = (unsigned short*)(ws + (56u << 20));
  (void)in_sizes; (void)n_in; (void)out_size; (void)ws_size;

  cvt_kernel<<<1024, 256, 0, stream>>>(x, xb, (NM * NE) / 8);
  cvt4_kernel<<<dim3(128, 4), 256, 0, stream>>>(Wq, Wk, Wv, Wo,
                                                wqb, wkb, wvb, wob, (NE * NE) / 8);

  gemm_bt<0><<<dim3(24, 64), 256, 0, stream>>>(xb, wqb, wkb, wvb, bq, bk, bv,
                                               Qw, Kw, Vtw, nullptr);
  attn_kernel<<<dim3(16, 64), 256, 0, stream>>>(Qw, Kw, Vtw, AOw);
  gemm_bt<1><<<dim3(8, 64), 256, 0, stream>>>(AOw, wob, nullptr, nullptr, bo,
                                              nullptr, nullptr,
                                              nullptr, nullptr, nullptr, out);
}